// Round 1
// baseline (983.118 us; speedup 1.0000x reference)
//
#include <hip/hip_runtime.h>

// ---------------------------------------------------------------------------
// QMWLNPairwiseAtomClassifier — restructured:
//  * gather-through-matmul: per-neighbor GEMMs done on distinct node rows
//  * separable pair attention: pair@W_att_h = U[b,i] + V[b,j]
//  * last-iter dead code removed (U2/U1 path), kernels only in last iter
// ---------------------------------------------------------------------------

constexpr int cB = 16, cNR = 96, cNG = 64;
constexpr int cAF = 98, cBF = 6;
constexpr int cH = 300, cQM = 160, cMAXNB = 10, cDEPTH = 4;
constexpr int cP = 2048;
constexpr int cF = 2 * cH + cQM;   // 760
constexpr int cD0 = cF + 10;       // 770

constexpr int Mres = cB * cNR;     // 1536
constexpr int Mrg  = cB * cNG;     // 1024

#define BM 64
#define BN 64
#define BK 16

struct GemmArgs {
  const float* A; const float* A2; const float* W; const float* W2;
  float* C; int M;
};

// C = act(A@W [+ A2@W2]); A:(M,K) row-major, W:(K,N) row-major.
// blockIdx.z picks between two independent problems (res / rg).
__global__ __launch_bounds__(256) void gemm_dual(
    GemmArgs g0, GemmArgs g1, int K, int K2, int N, int act)
{
  GemmArgs g = blockIdx.z ? g1 : g0;
  int m0 = blockIdx.y * BM;
  if (m0 >= g.M) return;
  int n0 = blockIdx.x * BN;
  __shared__ float As[BK][BM + 4];
  __shared__ float Bs[BK][BN + 4];
  int tid = threadIdx.x;
  int tx = tid & 15, ty = tid >> 4;
  float acc[4][4] = {};
  for (int src = 0; src < 2; ++src) {
    const float* Ap = src ? g.A2 : g.A;
    const float* Wp = src ? g.W2 : g.W;
    int Kc = src ? K2 : K;
    if (!Ap) continue;
    for (int k0 = 0; k0 < Kc; k0 += BK) {
      for (int t = tid; t < BM * BK; t += 256) {
        int kk = t & (BK - 1), m = t >> 4;
        int gm = m0 + m, gk = k0 + kk;
        As[kk][m] = (gm < g.M && gk < Kc) ? Ap[(size_t)gm * Kc + gk] : 0.f;
      }
      for (int t = tid; t < BK * BN; t += 256) {
        int n = t & (BN - 1), kk = t >> 6;
        int gn = n0 + n, gk = k0 + kk;
        Bs[kk][n] = (gn < N && gk < Kc) ? Wp[(size_t)gk * N + gn] : 0.f;
      }
      __syncthreads();
#pragma unroll
      for (int kk = 0; kk < BK; ++kk) {
        float a[4], b[4];
#pragma unroll
        for (int i = 0; i < 4; i++) a[i] = As[kk][ty * 4 + i];
#pragma unroll
        for (int j = 0; j < 4; j++) b[j] = Bs[kk][tx * 4 + j];
#pragma unroll
        for (int i = 0; i < 4; i++)
#pragma unroll
          for (int j = 0; j < 4; j++)
            acc[i][j] = fmaf(a[i], b[j], acc[i][j]);
      }
      __syncthreads();
    }
  }
#pragma unroll
  for (int i = 0; i < 4; i++) {
    int gm = m0 + ty * 4 + i;
    if (gm >= g.M) continue;
#pragma unroll
    for (int j = 0; j < 4; j++) {
      int gn = n0 + tx * 4 + j;
      if (gn < N) {
        float v = acc[i][j];
        if (act) v = fmaxf(v, 0.f);
        g.C[(size_t)gm * N + gn] = v;
      }
    }
  }
}

// nei_label[node,h] = sum_{k<nn} relu(Ra[ga(node,k),h] + Rb[gb(node,k),h])
__global__ __launch_bounds__(320) void nei_label_k(
    const float* __restrict__ Ra, const float* __restrict__ Rb,
    const int* __restrict__ ag, const int* __restrict__ bg,
    const int* __restrict__ nnb, float* __restrict__ out, int Nn)
{
  int node = blockIdx.x;
  int h = threadIdx.x;
  int nn = nnb[node];
  const int* agp = ag + (size_t)node * cMAXNB * 2;
  const int* bgp = bg + (size_t)node * cMAXNB * 2;
  if (h < cH) {
    float s = 0.f;
    for (int k = 0; k < nn; ++k) {
      int ra = agp[2 * k] * Nn + agp[2 * k + 1];
      int rb = bgp[2 * k] * Nn + bgp[2 * k + 1];
      s += fmaxf(Ra[(size_t)ra * cH + h] + Rb[(size_t)rb * cH + h], 0.f);
    }
    out[(size_t)node * cH + h] = s;
  }
}

// kernels[node,h] = (sum_{k<nn} Sa[ga,h]*Sb[gb,h]) * SelfR[node,h] * nmask[node]
__global__ __launch_bounds__(320) void kernels_k(
    const float* __restrict__ Sa, const float* __restrict__ Sb,
    const float* __restrict__ SelfR,
    const int* __restrict__ ag, const int* __restrict__ bg,
    const int* __restrict__ nnb, const float* __restrict__ nmask,
    float* __restrict__ out, int Nn)
{
  int node = blockIdx.x;
  int h = threadIdx.x;
  int nn = nnb[node];
  const int* agp = ag + (size_t)node * cMAXNB * 2;
  const int* bgp = bg + (size_t)node * cMAXNB * 2;
  if (h < cH) {
    float s = 0.f;
    for (int k = 0; k < nn; ++k) {
      int ra = agp[2 * k] * Nn + agp[2 * k + 1];
      int rb = bgp[2 * k] * Nn + bgp[2 * k + 1];
      s += Sa[(size_t)ra * cH + h] * Sb[(size_t)rb * cH + h];
    }
    out[(size_t)node * cH + h] = s * SelfR[(size_t)node * cH + h] * nmask[node];
  }
}

// per (b,i): att_j = sigmoid(sum_n relu(U[b,i,n]+V[b,j,n])*w_s[n]);
// ctx[b,i,:] = sum_j att_j * rgh[b,j,:]
__global__ __launch_bounds__(256) void att_ctx_k(
    const float* __restrict__ U, const float* __restrict__ V,
    const float* __restrict__ att_w, const float* __restrict__ rgh,
    float* __restrict__ ctx)
{
  int row = blockIdx.x;          // b*NR + i
  int b = row / cNR;
  __shared__ float Ur[cH];
  __shared__ float att[cNG];
  int tid = threadIdx.x;
  for (int n = tid; n < cH; n += 256) Ur[n] = U[(size_t)row * cH + n];
  __syncthreads();
  int wave = tid >> 6, lane = tid & 63;
  for (int j = wave; j < cNG; j += 4) {
    const float* Vr = V + (size_t)(b * cNG + j) * cH;
    float s = 0.f;
    for (int n = lane; n < cH; n += 64)
      s += fmaxf(Ur[n] + Vr[n], 0.f) * att_w[n];
    for (int off = 32; off; off >>= 1) s += __shfl_down(s, off);
    if (lane == 0) att[j] = 1.f / (1.f + expf(-s));
  }
  __syncthreads();
  for (int hh = tid; hh < cH; hh += 256) {
    float c = 0.f;
    for (int j = 0; j < cNG; ++j)
      c += att[j] * rgh[(size_t)(b * cNG + j) * cH + hh];
    ctx[(size_t)row * cH + hh] = c;
  }
}

__global__ __launch_bounds__(256) void assemble_h_k(
    const float* __restrict__ kern, const float* __restrict__ ctx,
    const float* __restrict__ qm, float* __restrict__ h)
{
  int node = blockIdx.x;
  for (int c = threadIdx.x; c < cF; c += 256) {
    float v;
    if (c < cH) v = kern[(size_t)node * cH + c];
    else if (c < 2 * cH) v = ctx[(size_t)node * cH + (c - cH)];
    else v = qm[(size_t)node * cQM + (c - 2 * cH)];
    h[(size_t)node * cF + c] = v;
  }
}

// rh = relu(x @ W0), x[p] = concat(h[s,i]+h[s,j], connect[p])
__global__ __launch_bounds__(256) void score_gemm_k(
    const float* __restrict__ h, const float* __restrict__ conn,
    const int* __restrict__ cm, const float* __restrict__ W0,
    float* __restrict__ rh)
{
  __shared__ float As[BK][BM + 4];
  __shared__ float Bs[BK][BN + 4];
  __shared__ int ridx1[BM], ridx2[BM];
  int tid = threadIdx.x;
  int tx = tid & 15, ty = tid >> 4;
  int m0 = blockIdx.y * BM, n0 = blockIdx.x * BN;
  if (tid < BM) {
    int p = m0 + tid;
    int s = cm[p * 3 + 0], i = cm[p * 3 + 1], j = cm[p * 3 + 2];
    ridx1[tid] = s * cNR + i;
    ridx2[tid] = s * cNR + j;
  }
  __syncthreads();
  float acc[4][4] = {};
  for (int k0 = 0; k0 < cD0; k0 += BK) {
    for (int t = tid; t < BM * BK; t += 256) {
      int kk = t & (BK - 1), m = t >> 4;
      int gk = k0 + kk, p = m0 + m;
      float v = 0.f;
      if (gk < cD0) {
        if (gk < cF)
          v = h[(size_t)ridx1[m] * cF + gk] + h[(size_t)ridx2[m] * cF + gk];
        else
          v = conn[(size_t)p * 10 + (gk - cF)];
      }
      As[kk][m] = v;
    }
    for (int t = tid; t < BK * BN; t += 256) {
      int n = t & (BN - 1), kk = t >> 6;
      int gn = n0 + n, gk = k0 + kk;
      Bs[kk][n] = (gn < cD0 && gk < cD0) ? W0[(size_t)gk * cD0 + gn] : 0.f;
    }
    __syncthreads();
#pragma unroll
    for (int kk = 0; kk < BK; ++kk) {
      float a[4], b[4];
#pragma unroll
      for (int i = 0; i < 4; i++) a[i] = As[kk][ty * 4 + i];
#pragma unroll
      for (int j = 0; j < 4; j++) b[j] = Bs[kk][tx * 4 + j];
#pragma unroll
      for (int i = 0; i < 4; i++)
#pragma unroll
        for (int j = 0; j < 4; j++)
          acc[i][j] = fmaf(a[i], b[j], acc[i][j]);
    }
    __syncthreads();
  }
#pragma unroll
  for (int i = 0; i < 4; i++) {
    int gm = m0 + ty * 4 + i;
#pragma unroll
    for (int j = 0; j < 4; j++) {
      int gn = n0 + tx * 4 + j;
      if (gn < cD0)
        rh[(size_t)gm * cD0 + gn] = fmaxf(acc[i][j], 0.f);
    }
  }
}

// one wave per p: val = rh[p]·W_score; atomic segment sums
__global__ __launch_bounds__(256) void score_reduce_k(
    const float* __restrict__ rh, const float* __restrict__ Wsc,
    const int* __restrict__ cm, float* __restrict__ segsum,
    float* __restrict__ segcnt)
{
  int p = blockIdx.x * 4 + (threadIdx.x >> 6);
  int lane = threadIdx.x & 63;
  float s = 0.f;
  for (int d = lane; d < cD0; d += 64) s += rh[(size_t)p * cD0 + d] * Wsc[d];
  for (int off = 32; off; off >>= 1) s += __shfl_down(s, off);
  if (lane == 0) {
    atomicAdd(&segsum[cm[p * 3]], s);
    atomicAdd(&segcnt[cm[p * 3]], 1.f);
  }
}

__global__ void finalize_k(const float* __restrict__ segsum,
                           const float* __restrict__ segcnt,
                           float* __restrict__ out)
{
  int b = threadIdx.x;
  if (b < cB) out[b] = segsum[b] / segcnt[b];
}

extern "C" void kernel_launch(void* const* d_in, const int* in_sizes, int n_in,
                              void* d_out, int out_size, void* d_ws, size_t ws_size,
                              hipStream_t stream)
{
  (void)in_sizes; (void)n_in; (void)out_size; (void)ws_size;
  const float* res_atom = (const float*)d_in[0];
  const float* res_bond = (const float*)d_in[1];
  const int*   res_ag   = (const int*)d_in[2];
  const int*   res_bg   = (const int*)d_in[3];
  const int*   res_nnb  = (const int*)d_in[4];
  const float* res_mask = (const float*)d_in[5];
  const float* rg_atom  = (const float*)d_in[6];
  const float* rg_bond  = (const float*)d_in[7];
  const int*   rg_ag    = (const int*)d_in[8];
  const int*   rg_bg    = (const int*)d_in[9];
  const int*   rg_nnb   = (const int*)d_in[10];
  const float* rg_mask  = (const float*)d_in[11];
  const int*   core     = (const int*)d_in[12];
  const float* qm       = (const float*)d_in[13];
  const float* connect  = (const float*)d_in[14];
  const float* rW_atom  = (const float*)d_in[15];
  const float* rW_na    = (const float*)d_in[16];
  const float* rW_nb    = (const float*)d_in[17];
  const float* rW_self  = (const float*)d_in[18];
  const float* rW_U2    = (const float*)d_in[19];
  const float* rW_U1    = (const float*)d_in[20];
  const float* gW_atom  = (const float*)d_in[21];
  const float* gW_na    = (const float*)d_in[22];
  const float* gW_nb    = (const float*)d_in[23];
  const float* gW_self  = (const float*)d_in[24];
  const float* gW_U2    = (const float*)d_in[25];
  const float* gW_U1    = (const float*)d_in[26];
  const float* W_att_h  = (const float*)d_in[27];
  const float* W_att_s  = (const float*)d_in[28];
  const float* W_score0 = (const float*)d_in[29];
  const float* W_score  = (const float*)d_in[30];
  float* out = (float*)d_out;

  float* ws = (float*)d_ws;
  size_t off = 0;
  auto alloc = [&](size_t n) {
    float* p = ws + off;
    off += (n + 63) & ~(size_t)63;
    return p;
  };
  float* afA_r = alloc((size_t)Mres * cH);
  float* afB_r = alloc((size_t)Mres * cH);
  float* Rb_r  = alloc((size_t)Mres * cH);
  float* Sb_r  = alloc((size_t)Mres * cH);
  float* Ra_r  = alloc((size_t)Mres * cH);
  float* nei_r = alloc((size_t)Mres * cH);
  float* kern_r= alloc((size_t)Mres * cH);
  float* afA_g = alloc((size_t)Mrg * cH);
  float* afB_g = alloc((size_t)Mrg * cH);
  float* Rb_g  = alloc((size_t)Mrg * cH);
  float* Sb_g  = alloc((size_t)Mrg * cH);
  float* Ra_g  = alloc((size_t)Mrg * cH);
  float* nei_g = alloc((size_t)Mrg * cH);
  float* kern_g= alloc((size_t)Mrg * cH);
  float* U     = alloc((size_t)Mres * cH);
  float* V     = alloc((size_t)Mrg * cH);
  float* ctx   = alloc((size_t)Mres * cH);
  float* h760  = alloc((size_t)Mres * cF);
  float* rh    = alloc((size_t)cP * cD0);
  float* segsum = alloc(64);            // [0..15] sums, [16..31] counts
  float* segcnt = segsum + 16;

  dim3 blk(256);
  dim3 ggrid((cH + BN - 1) / BN, (Mres + BM - 1) / BM, 2);  // (5,24,2)

  // af0 = relu(atom @ W_atom)
  {
    GemmArgs a{res_atom, nullptr, rW_atom, nullptr, afA_r, Mres};
    GemmArgs b{rg_atom,  nullptr, gW_atom, nullptr, afA_g, Mrg};
    gemm_dual<<<ggrid, blk, 0, stream>>>(a, b, cAF, 0, cH, 1);
  }
  // Rb = bond @ W_U2_bottom  (no relu; relu happens after sum in nei_label)
  {
    GemmArgs a{res_bond, nullptr, rW_U2 + (size_t)cH * cH, nullptr, Rb_r, Mres};
    GemmArgs b{rg_bond,  nullptr, gW_U2 + (size_t)cH * cH, nullptr, Rb_g, Mrg};
    gemm_dual<<<ggrid, blk, 0, stream>>>(a, b, cBF, 0, cH, 0);
  }
  // Sb = relu(bond @ W_nei_bond)
  {
    GemmArgs a{res_bond, nullptr, rW_nb, nullptr, Sb_r, Mres};
    GemmArgs b{rg_bond,  nullptr, gW_nb, nullptr, Sb_g, Mrg};
    gemm_dual<<<ggrid, blk, 0, stream>>>(a, b, cBF, 0, cH, 1);
  }

  float* af_r = afA_r; float* afo_r = afB_r;
  float* af_g = afA_g; float* afo_g = afB_g;
  for (int t = 0; t < cDEPTH - 1; ++t) {
    // Ra = af @ W_U2_top
    {
      GemmArgs a{af_r, nullptr, rW_U2, nullptr, Ra_r, Mres};
      GemmArgs b{af_g, nullptr, gW_U2, nullptr, Ra_g, Mrg};
      gemm_dual<<<ggrid, blk, 0, stream>>>(a, b, cH, 0, cH, 0);
    }
    nei_label_k<<<dim3(Mres), dim3(320), 0, stream>>>(Ra_r, Rb_r, res_ag, res_bg, res_nnb, nei_r, cNR);
    nei_label_k<<<dim3(Mrg),  dim3(320), 0, stream>>>(Ra_g, Rb_g, rg_ag, rg_bg, rg_nnb, nei_g, cNG);
    // af' = relu(af @ W_U1_top + nei @ W_U1_bottom)
    {
      GemmArgs a{af_r, nei_r, rW_U1, rW_U1 + (size_t)cH * cH, afo_r, Mres};
      GemmArgs b{af_g, nei_g, gW_U1, gW_U1 + (size_t)cH * cH, afo_g, Mrg};
      gemm_dual<<<ggrid, blk, 0, stream>>>(a, b, cH, cH, cH, 1);
    }
    { float* t1 = af_r; af_r = afo_r; afo_r = t1; }
    { float* t2 = af_g; af_g = afo_g; afo_g = t2; }
  }

  // final iteration: Sa = relu(af@W_nei_atom), SelfR = relu(af@W_self)
  {
    GemmArgs a{af_r, nullptr, rW_na, nullptr, Ra_r, Mres};
    GemmArgs b{af_g, nullptr, gW_na, nullptr, Ra_g, Mrg};
    gemm_dual<<<ggrid, blk, 0, stream>>>(a, b, cH, 0, cH, 1);
  }
  {
    GemmArgs a{af_r, nullptr, rW_self, nullptr, nei_r, Mres};
    GemmArgs b{af_g, nullptr, gW_self, nullptr, nei_g, Mrg};
    gemm_dual<<<ggrid, blk, 0, stream>>>(a, b, cH, 0, cH, 1);
  }
  kernels_k<<<dim3(Mres), dim3(320), 0, stream>>>(Ra_r, Sb_r, nei_r, res_ag, res_bg, res_nnb, res_mask, kern_r, cNR);
  kernels_k<<<dim3(Mrg),  dim3(320), 0, stream>>>(Ra_g, Sb_g, nei_g, rg_ag, rg_bg, rg_nnb, rg_mask, kern_g, cNG);

  // U = res_h @ W_att_h ; V = rg_h @ W_att_h
  {
    GemmArgs a{kern_r, nullptr, W_att_h, nullptr, U, Mres};
    GemmArgs b{kern_g, nullptr, W_att_h, nullptr, V, Mrg};
    gemm_dual<<<ggrid, blk, 0, stream>>>(a, b, cH, 0, cH, 0);
  }
  att_ctx_k<<<dim3(Mres), blk, 0, stream>>>(U, V, W_att_s, kern_g, ctx);
  assemble_h_k<<<dim3(Mres), blk, 0, stream>>>(kern_r, ctx, qm, h760);

  score_gemm_k<<<dim3((cD0 + BN - 1) / BN, cP / BM), blk, 0, stream>>>(h760, connect, core, W_score0, rh);
  hipMemsetAsync(segsum, 0, 32 * sizeof(float), stream);
  score_reduce_k<<<dim3(cP / 4), blk, 0, stream>>>(rh, W_score, core, segsum, segcnt);
  finalize_k<<<dim3(1), dim3(64), 0, stream>>>(segsum, segcnt, out);
}